// Round 9
// baseline (167.672 us; speedup 1.0000x reference)
//
#include <hip/hip_runtime.h>
#include <math.h>

#define TN 8192
#define AN 128
#define NW20 (TN - 20)   // 8172
#define NW10 (TN - 10)   // 8182

// ---- k_main grid ranges ----
#define NSL     32       // gram slices (256 rows each; fp32 acc validated R1)
#define NB_ROW  512      // 16 rows/block
#define NB_R20  511      // 16 windows/block (4 waves x strip of 4)
#define NB_R10  512
#define RB0     NSL                       // 32
#define R20B0   (RB0 + NB_ROW)            // 544
#define R10B0   (R20B0 + NB_R20)          // 1055
#define NB_WORK (R10B0 + NB_R10)          // 1567

// ---- workspace double-layout ----
#define WS_STD0 0
#define WS_STDL 1
#define WS_BLK  8                         // NB_WORK*2 per-block scalar slots
#define WS_DEND 4096

// rolling off-diag corr via C.sum() = sum_t (sum_i z_ti)^2; butterfly with
// lane-compression; 4 consecutive windows per wave from one register strip.
// Verified R4/R6 (absmax 7.45e-9). Lane owns columns {2*lane, 2*lane+1}.
template <int W>
__device__ __forceinline__ void roll_strip4(const float* __restrict__ x,
                                            int s0, int nwin, int lane,
                                            double& accA, double& accB) {
  constexpr int NR = W + 3;
  float a0[NR], a1[NR];
#pragma unroll
  for (int t = 0; t < NR; ++t) {
    int r = s0 + t; r = (r < TN) ? r : (TN - 1);
    float2 v = *(const float2*)(x + (size_t)r * AN + 2 * lane);
    a0[t] = v.x; a1[t] = v.y;
  }
#pragma unroll
  for (int w4 = 0; w4 < 4; ++w4) {
    int s = s0 + w4;
    if (s < nwin) {
      float sf0 = 0.f, sf1 = 0.f;
#pragma unroll
      for (int t = 0; t < W; ++t) { sf0 += a0[w4 + t]; sf1 += a1[w4 + t]; }
      float mu0 = sf0 / W, mu1 = sf1 / W;
      float v0 = 0.f, v1 = 0.f;
#pragma unroll
      for (int t = 0; t < W; ++t) {
        float d0 = a0[w4 + t] - mu0, d1 = a1[w4 + t] - mu1;
        v0 += d0 * d0; v1 += d1 * d1;
      }
      float i0 = 1.0f / sqrtf(v0), i1 = 1.0f / sqrtf(v1);
      float q[W];
#pragma unroll
      for (int t = 0; t < W; ++t)
        q[t] = (a0[w4 + t] - mu0) * i0 + (a1[w4 + t] - mu1) * i1;
      int n = W;
#pragma unroll
      for (int o = 1; o <= 32; o <<= 1) {
#pragma unroll
        for (int k = 0; k < n; ++k) q[k] += __shfl_xor(q[k], o);
        if (n > 1) {
          int nh = n >> 1;
          bool hi = (lane & o) != 0;
#pragma unroll
          for (int k = 0; k < nh; ++k) q[k] = hi ? q[2 * k + 1] : q[2 * k];
          if (n & 1) { q[nh] = q[2 * nh]; n = nh + 1; } else { n = nh; }
        }
      }
      float alpha = (W == 20) ? ((lane & 16) ? 0.125f : 0.5f)
                              : ((lane & 8) ? 0.0625f : 0.25f);
      float r = q[0] * q[0] * alpha;
#pragma unroll
      for (int o = 32; o; o >>= 1) r += __shfl_xor(r, o);
      if (lane == 0) {
        double off = ((double)r - (double)AN) / ((double)AN * (AN - 1));
        if (W == 20) {
          accA += (off > 0.7) ? 1.0 : 0.0;
        } else {
          accA += off;
          if (s >= TN - W - 5) accB += off;
        }
      }
    }
  }
}

// ============ phase A: all data-parallel work, deterministic slots =======
__global__ void __launch_bounds__(256) k_main(const float* __restrict__ x,
                                              double* __restrict__ wsd,
                                              float* __restrict__ pc,
                                              float* __restrict__ pdg,
                                              float* __restrict__ pg) {
  __shared__ union {
    float stage[8][AN];
    double tacc[4][2];
  } sm;
  const int b = blockIdx.x;
  const int tid = threadIdx.x;
  const int lane = tid & 63;
  const int w = tid >> 6;

  if (b < NSL) {
    // ---- gram slice: 256 rows, 8x8 register tiles ----
    int i0 = (tid >> 4) * 8;
    int j0 = (tid & 15) * 8;
    int lrow = tid >> 5;
    int lcol = (tid & 31) * 4;
    const float* xs = x + (size_t)b * 256 * AN;
    float acc[8][8];
#pragma unroll
    for (int a = 0; a < 8; ++a)
#pragma unroll
      for (int c = 0; c < 8; ++c) acc[a][c] = 0.f;
    float4 v = *(const float4*)(xs + lrow * AN + lcol);
    for (int it = 0; it < 32; ++it) {
      __syncthreads();
      *(float4*)(&sm.stage[lrow][lcol]) = v;
      __syncthreads();
      if (it + 1 < 32)
        v = *(const float4*)(xs + ((it + 1) * 8 + lrow) * AN + lcol);
#pragma unroll
      for (int r = 0; r < 8; ++r) {
        float aa[8], bb[8];
        *(float4*)(aa) = *(const float4*)(&sm.stage[r][i0]);
        *(float4*)(aa + 4) = *(const float4*)(&sm.stage[r][i0 + 4]);
        *(float4*)(bb) = *(const float4*)(&sm.stage[r][j0]);
        *(float4*)(bb + 4) = *(const float4*)(&sm.stage[r][j0 + 4]);
#pragma unroll
        for (int ai = 0; ai < 8; ++ai)
#pragma unroll
          for (int bj = 0; bj < 8; ++bj)
            acc[ai][bj] = fmaf(aa[ai], bb[bj], acc[ai][bj]);
      }
    }
    float* dst = pg + (size_t)b * (AN * AN);
#pragma unroll
    for (int ai = 0; ai < 8; ++ai)
#pragma unroll
      for (int bj = 0; bj < 8; bj += 4)
        *(float4*)(dst + (i0 + ai) * AN + j0 + bj) =
            make_float4(acc[ai][bj], acc[ai][bj + 1], acc[ai][bj + 2],
                        acc[ai][bj + 3]);
    if ((tid >> 4) == (tid & 15)) {
#pragma unroll
      for (int k = 0; k < 8; ++k) pdg[b * AN + i0 + k] = acc[k][k];
    }
    if (tid < AN) {
      float cs = 0.f;
      for (int r = 0; r < 256; ++r) cs += xs[r * AN + tid];
      pc[b * AN + tid] = cs;
    }
    return;
  }

  if (b < R20B0) {
    // ---- per-row std + sign counts, 16 rows/block, float2 cols ----
    int rb = b - RB0;
    double sstd = 0.0, sconc = 0.0;
    for (int rr = 0; rr < 4; ++rr) {
      int t = rb * 16 + w * 4 + rr;
      float2 xv = *(const float2*)(x + (size_t)t * AN + 2 * lane);
      float x0 = xv.x, x1 = xv.y;
      float s = x0 + x1;
#pragma unroll
      for (int o = 32; o; o >>= 1) s += __shfl_xor(s, o);
      float mean = s * (1.0f / AN);
      float d0 = x0 - mean, d1 = x1 - mean;
      float q = d0 * d0 + d1 * d1;
#pragma unroll
      for (int o = 32; o; o >>= 1) q += __shfl_xor(q, o);
      float sd = sqrtf(q / (float)(AN - 1));
      int pk = (int)(x0 < 0.f) + (int)(x1 < 0.f)
             + (((int)(x0 == 0.f) + (int)(x1 == 0.f)) << 10)
             + (((int)(x0 > 0.f) + (int)(x1 > 0.f)) << 20);
#pragma unroll
      for (int o = 32; o; o >>= 1) pk += __shfl_xor(pk, o);
      if (lane == 0) {
        int nn = pk & 1023, nz = (pk >> 10) & 1023, np = (pk >> 20) & 1023;
        sconc += (double)nn * nn + (double)nz * nz + (double)np * np;
        sstd += (double)sd;
        if (t == 0) wsd[WS_STD0] = (double)sd;
        if (t == TN - 1) wsd[WS_STDL] = (double)sd;
      }
    }
    if (lane == 0) { sm.tacc[w][0] = sstd; sm.tacc[w][1] = sconc; }
    __syncthreads();
    if (tid == 0) {
      wsd[WS_BLK + (size_t)b * 2 + 0] =
          sm.tacc[0][0] + sm.tacc[1][0] + sm.tacc[2][0] + sm.tacc[3][0];
      wsd[WS_BLK + (size_t)b * 2 + 1] =
          sm.tacc[0][1] + sm.tacc[1][1] + sm.tacc[2][1] + sm.tacc[3][1];
    }
    return;
  }

  if (b < R10B0) {
    int s0 = (b - R20B0) * 16 + w * 4;
    double cnt = 0.0, dummy = 0.0;
    roll_strip4<20>(x, s0, NW20, lane, cnt, dummy);
    if (lane == 0) { sm.tacc[w][0] = cnt; }
    __syncthreads();
    if (tid == 0)
      wsd[WS_BLK + (size_t)b * 2 + 0] =
          sm.tacc[0][0] + sm.tacc[1][0] + sm.tacc[2][0] + sm.tacc[3][0];
    return;
  }

  {
    int s0 = (b - R10B0) * 16 + w * 4;
    double s10 = 0.0, s10l5 = 0.0;
    roll_strip4<10>(x, s0, NW10, lane, s10, s10l5);
    if (lane == 0) { sm.tacc[w][0] = s10; sm.tacc[w][1] = s10l5; }
    __syncthreads();
    if (tid == 0) {
      wsd[WS_BLK + (size_t)b * 2 + 0] =
          sm.tacc[0][0] + sm.tacc[1][0] + sm.tacc[2][0] + sm.tacc[3][0];
      wsd[WS_BLK + (size_t)b * 2 + 1] =
          sm.tacc[0][1] + sm.tacc[1][1] + sm.tacc[2][1] + sm.tacc[3][1];
    }
  }
}

// ==== phase B: fold -> corr(LDS) -> spec + power iter + MLP + output =====
__global__ void __launch_bounds__(1024) k_tail(
    const float* __restrict__ x, const float* __restrict__ pos,
    const float* __restrict__ w1, const float* __restrict__ b1,
    const float* __restrict__ gamma, const float* __restrict__ beta,
    const float* __restrict__ w2, const float* __restrict__ b2,
    const float* __restrict__ w3, const float* __restrict__ b3,
    const double* __restrict__ wsd, const float* __restrict__ pc,
    const float* __restrict__ pdg, const float* __restrict__ pg,
    float* __restrict__ out) {
  __shared__ float cS[AN * 130];          // corr, padded rows
  __shared__ double muD[AN], dD[AN];
  __shared__ double wred[16][8];
  __shared__ double tiny[8];
  __shared__ float vv[AN], prt[1024], un[AN], red[2];
  __shared__ float f[2 * AN], h1[AN], h2[64], lg[3];
  const int tid = threadIdx.x;
  const int lane = tid & 63;
  const int w = tid >> 6;                 // 16 waves

  if (tid < 2 * AN)
    f[tid] = (tid < AN) ? x[(size_t)(TN - 1) * AN + tid] : pos[tid - AN];
  if (tid < AN) {
    double cs = 0.0, dg = 0.0;
    for (int s = 0; s < NSL; ++s) {
      cs += (double)pc[s * AN + tid];
      dg += (double)pdg[s * AN + tid];
    }
    double mu = cs / (double)TN;
    muD[tid] = mu;
    dD[tid] = sqrt(dg - (double)TN * mu * mu);
  }
  __syncthreads();
  // ---- fold 32 fp32 partial grams -> corr in LDS + spec sums ----
  double c0 = 0.0, c1 = 0.0, c2 = 0.0;
#pragma unroll
  for (int g = 0; g < 4; ++g) {
    int base = tid * 4 + g * 4096;
    float4 s4 = make_float4(0.f, 0.f, 0.f, 0.f);
    for (int s = 0; s < NSL; ++s) {
      float4 v = *(const float4*)(pg + (size_t)s * (AN * AN) + base);
      s4.x += v.x; s4.y += v.y; s4.z += v.z; s4.w += v.w;
    }
    int i = base >> 7, j = base & (AN - 1);
    double mi = muD[i];
    double cv[4] = {(double)s4.x, (double)s4.y, (double)s4.z, (double)s4.w};
#pragma unroll
    for (int k = 0; k < 4; ++k) {
      double c = (cv[k] - (double)TN * mi * muD[j + k]) / (dD[i] * dD[j + k]);
      cS[i * 130 + j + k] = (float)c;
      c0 += c;
      c1 += fabs(c);
      if (i == (j + k)) c2 += c;
    }
  }
  // ---- scalar folds over per-block slots (joint wave reduction) ----
  double v0 = 0, v1 = 0, v2 = 0, v3 = 0, v4 = 0;
  for (int k = RB0 + tid; k < NB_WORK; k += 1024) {
    const double* p = wsd + WS_BLK + (size_t)k * 2;
    if (k < R20B0) { v0 += p[0]; v1 += p[1]; }
    else if (k < R10B0) v2 += p[0];
    else { v3 += p[0]; v4 += p[1]; }
  }
#pragma unroll
  for (int o = 32; o; o >>= 1) {
    v0 += __shfl_xor(v0, o); v1 += __shfl_xor(v1, o);
    v2 += __shfl_xor(v2, o); v3 += __shfl_xor(v3, o);
    v4 += __shfl_xor(v4, o);
    c0 += __shfl_xor(c0, o); c1 += __shfl_xor(c1, o);
    c2 += __shfl_xor(c2, o);
  }
  if (lane == 0) {
    wred[w][0] = v0; wred[w][1] = v1; wred[w][2] = v2; wred[w][3] = v3;
    wred[w][4] = v4; wred[w][5] = c0; wred[w][6] = c1; wred[w][7] = c2;
  }
  if (tid < AN) vv[tid] = 1.0f;
  __syncthreads();
  if (tid < 8) {
    double s = 0.0;
    for (int k = 0; k < 16; ++k) s += wred[k][tid];
    tiny[tid] = s;
  }
  __syncthreads();
  // ---- power iteration, 12 iters, corr in LDS, 8 segs/row ----
  const int ri = tid & (AN - 1);
  const int seg = tid >> 7;               // 0..7
  const float* rowp = &cS[ri * 130 + seg * 16];
  float lam = 0.0f;
  for (int it = 0; it < 12; ++it) {
    const float* vp = &vv[seg * 16];
    float acc = 0.f;
#pragma unroll
    for (int k = 0; k < 16; ++k) acc += rowp[k] * vp[k];
    prt[tid] = acc;
    __syncthreads();
    if (tid < AN) {
      float u = 0.f;
#pragma unroll
      for (int s = 0; s < 8; ++s) u += prt[tid + 128 * s];
      un[tid] = u;
      float sq = u * u;
#pragma unroll
      for (int o = 32; o; o >>= 1) sq += __shfl_xor(sq, o);
      if (lane == 0) red[w] = sq;
    }
    __syncthreads();
    lam = sqrtf(red[0] + red[1]);
    if (tid < AN) vv[tid] = un[tid] / lam;
    __syncthreads();
  }
  // ---- MLP: layer1 split 8 K-groups of 32 ----
  {
    int n = tid & 127, g = tid >> 7;
    float acc = 0.f;
    const float* wcol = w1 + (g * 32) * AN + n;
    const float* fv = f + g * 32;
#pragma unroll
    for (int k = 0; k < 32; ++k) acc = fmaf(fv[k], wcol[k * AN], acc);
    prt[tid] = acc;
  }
  __syncthreads();
  if (tid < AN) {
    float acc = b1[tid];
#pragma unroll
    for (int s = 0; s < 8; ++s) acc += prt[tid + 128 * s];
    acc = fmaxf(acc, 0.0f);
    h1[tid] = gamma[tid] * (acc / sqrtf(1.0f + 1e-5f)) + beta[tid];
  }
  __syncthreads();
  if (tid < 512) {
    int n = tid & 63, g = tid >> 6;       // 8 K-groups of 16
    float acc = 0.f;
    const float* wcol = w2 + (g * 16) * 64 + n;
    const float* hv = h1 + g * 16;
#pragma unroll
    for (int k = 0; k < 16; ++k) acc = fmaf(hv[k], wcol[k * 64], acc);
    prt[tid] = acc;
  }
  __syncthreads();
  if (tid < 64) {
    float acc = b2[tid];
#pragma unroll
    for (int s = 0; s < 8; ++s) acc += prt[tid + 64 * s];
    h2[tid] = fmaxf(acc, 0.0f);
  }
  __syncthreads();
  if (tid < 3) {
    float acc = b3[tid];
    for (int k = 0; k < 64; ++k) acc = fmaf(h2[k], w3[k * 3 + tid], acc);
    lg[tid] = acc;
  }
  __syncthreads();
  if (tid != 0) return;
  float m = fmaxf(lg[0], fmaxf(lg[1], lg[2]));
  float e0 = expf(lg[0] - m), e1 = expf(lg[1] - m), e2 = expf(lg[2] - m);
  double sev = (double)(e2 / (e0 + e1 + e2));
  double sumstd = tiny[0], conc = tiny[1], cnt20 = tiny[2];
  double sum10 = tiny[3], sum10l5 = tiny[4];
  double csum = tiny[5], cabs = tiny[6], ctrace = tiny[7];
  double avg_disp = sumstd / (double)TN;
  double trend = -(wsd[WS_STDL] - wsd[WS_STD0]) / (double)(TN - 1);
  double hi = trend / (avg_disp + 1e-6) + 0.5;
  hi = fmin(1.0, fmax(0.0, hi));
  double avg_corr = (csum - ctrace) / ((double)AN * (AN - 1));
  double sync_ind = (double)lam / (double)AN;
  double sync_risk = fmin(1.0, sync_ind * avg_corr);
  double pl = cnt20 / (double)(TN - 20);
  double rd = 1.0 - cabs / ((double)AN * AN);
  double pasum = 0.0, pamax = 0.0;
  for (int k = 0; k < AN; ++k) {
    double pa = fabs((double)pos[k]);
    pasum += pa;
    if (pa > pamax) pamax = pa;
  }
  double pd = 1.0 - pamax / pasum;
  double dl = 1.0 - sqrt(rd * pd);
  double recent = sum10l5 / 5.0;
  double hist = (sum10 - sum10l5) / (double)(TN - 10 - 5);
  double sraw = (recent - hist) / hist;
  sraw = fmin(1.0, fmax(0.0, sraw));
  double surge = (hist > 0.0) ? sraw : 0.0;
  double ac = (conc / (double)TN - (double)AN) / ((double)AN * (AN - 1));
  double pcup = fmin(1.0, fmax(0.0, (ac - 0.5) * 2.0));
  double cr = (hi + sync_risk + dl) / 3.0;
  out[0] = (float)hi;
  out[1] = (float)sev;
  out[2] = (float)sync_risk;
  out[3] = (float)pl;
  out[4] = (float)dl;
  out[5] = (float)surge;
  out[6] = (float)pcup;
  out[7] = (float)cr;
}

extern "C" void kernel_launch(void* const* d_in, const int* in_sizes, int n_in,
                              void* d_out, int out_size, void* d_ws, size_t ws_size,
                              hipStream_t stream) {
  const float* x     = (const float*)d_in[0];
  const float* pos   = (const float*)d_in[1];
  const float* w1    = (const float*)d_in[2];
  const float* b1    = (const float*)d_in[3];
  const float* gamma = (const float*)d_in[4];
  const float* beta  = (const float*)d_in[5];
  const float* w2    = (const float*)d_in[6];
  const float* b2    = (const float*)d_in[7];
  const float* w3    = (const float*)d_in[8];
  const float* b3    = (const float*)d_in[9];
  float* out = (float*)d_out;
  double* wsd = (double*)d_ws;
  float* pc   = (float*)(wsd + WS_DEND);               // [32*128]
  float* pdg  = pc + NSL * AN;                         // [32*128]
  float* pg   = pdg + NSL * AN;                        // [32*16384]

  k_main<<<NB_WORK, 256, 0, stream>>>(x, wsd, pc, pdg, pg);
  k_tail<<<1, 1024, 0, stream>>>(x, pos, w1, b1, gamma, beta, w2, b2, w3, b3,
                                 wsd, pc, pdg, pg, out);
}

// Round 10
// 126.196 us; speedup vs baseline: 1.3287x; 1.3287x over previous
//
#include <hip/hip_runtime.h>
#include <math.h>

#define TN 8192
#define AN 128
#define NW20 (TN - 20)   // 8172
#define NW10 (TN - 10)   // 8182

// ---- k_main grid ranges ----
#define NB_GRAM 128      // 64 rows/slice (R6-measured balanced config)
#define NB_ROW  512      // 16 rows/block
#define NB_R20  511      // 16 windows/block (4 waves x strip of 4)
#define NB_R10  512
#define RB0     NB_GRAM                   // 128
#define R20B0   (RB0 + NB_ROW)            // 640
#define R10B0   (R20B0 + NB_R20)          // 1151
#define NB_WORK (R10B0 + NB_R10)          // 1663

// ---- workspace double-layout ----
#define WS_STD0 0
#define WS_STDL 1
#define WS_SPEC 8                    // 64*3 {sum, sumabs, trace}
#define WS_BLK  200                  // NB_WORK*2 per-block scalar slots
#define WS_DEND 4096

// rolling off-diag corr via C.sum() = sum_t (sum_i z_ti)^2; butterfly with
// lane-compression; 4 consecutive windows per wave from one register strip.
// Verified R4/R6/R9 (absmax 7.45e-9). Lane owns columns {2*lane, 2*lane+1}.
template <int W>
__device__ __forceinline__ void roll_strip4(const float* __restrict__ x,
                                            int s0, int nwin, int lane,
                                            double& accA, double& accB) {
  constexpr int NR = W + 3;
  float a0[NR], a1[NR];
#pragma unroll
  for (int t = 0; t < NR; ++t) {
    int r = s0 + t; r = (r < TN) ? r : (TN - 1);
    float2 v = *(const float2*)(x + (size_t)r * AN + 2 * lane);
    a0[t] = v.x; a1[t] = v.y;
  }
#pragma unroll
  for (int w4 = 0; w4 < 4; ++w4) {
    int s = s0 + w4;
    if (s < nwin) {
      float sf0 = 0.f, sf1 = 0.f;
#pragma unroll
      for (int t = 0; t < W; ++t) { sf0 += a0[w4 + t]; sf1 += a1[w4 + t]; }
      float mu0 = sf0 / W, mu1 = sf1 / W;
      float v0 = 0.f, v1 = 0.f;
#pragma unroll
      for (int t = 0; t < W; ++t) {
        float d0 = a0[w4 + t] - mu0, d1 = a1[w4 + t] - mu1;
        v0 += d0 * d0; v1 += d1 * d1;
      }
      float i0 = 1.0f / sqrtf(v0), i1 = 1.0f / sqrtf(v1);
      float q[W];
#pragma unroll
      for (int t = 0; t < W; ++t)
        q[t] = (a0[w4 + t] - mu0) * i0 + (a1[w4 + t] - mu1) * i1;
      int n = W;
#pragma unroll
      for (int o = 1; o <= 32; o <<= 1) {
#pragma unroll
        for (int k = 0; k < n; ++k) q[k] += __shfl_xor(q[k], o);
        if (n > 1) {
          int nh = n >> 1;
          bool hi = (lane & o) != 0;
#pragma unroll
          for (int k = 0; k < nh; ++k) q[k] = hi ? q[2 * k + 1] : q[2 * k];
          if (n & 1) { q[nh] = q[2 * nh]; n = nh + 1; } else { n = nh; }
        }
      }
      float alpha = (W == 20) ? ((lane & 16) ? 0.125f : 0.5f)
                              : ((lane & 8) ? 0.0625f : 0.25f);
      float r = q[0] * q[0] * alpha;
#pragma unroll
      for (int o = 32; o; o >>= 1) r += __shfl_xor(r, o);
      if (lane == 0) {
        double off = ((double)r - (double)AN) / ((double)AN * (AN - 1));
        if (W == 20) {
          accA += (off > 0.7) ? 1.0 : 0.0;
        } else {
          accA += off;
          if (s >= TN - W - 5) accB += off;
        }
      }
    }
  }
}

// ============ phase A: all data-parallel work, deterministic slots =======
__global__ void __launch_bounds__(256) k_main(const float* __restrict__ x,
                                              double* __restrict__ wsd,
                                              float* __restrict__ pc,
                                              float* __restrict__ pdg,
                                              float* __restrict__ pg) {
  __shared__ union {
    float stage[16][AN];              // 8 KB: 16-row chunks, half the barriers
    double tacc[4][2];
  } sm;
  const int b = blockIdx.x;
  const int tid = threadIdx.x;
  const int lane = tid & 63;
  const int w = tid >> 6;

  if (b < NB_GRAM) {
    // ---- gram slice: 64 rows, 8x8 register tiles, 16-row stage chunks ----
    // (accumulation order over t identical to R6 -> bit-identical result)
    int i0 = (tid >> 4) * 8;
    int j0 = (tid & 15) * 8;
    int lrow = tid >> 4;               // 0..15 (16 rows, 16 threads each)
    int lcol = (tid & 15) * 8;         // 0..120, 8 floats per thread
    const float* xs = x + (size_t)b * 64 * AN;
    float acc[8][8];
#pragma unroll
    for (int a = 0; a < 8; ++a)
#pragma unroll
      for (int c = 0; c < 8; ++c) acc[a][c] = 0.f;
    float4 va = *(const float4*)(xs + lrow * AN + lcol);
    float4 vb = *(const float4*)(xs + lrow * AN + lcol + 4);
    for (int it = 0; it < 4; ++it) {
      __syncthreads();
      *(float4*)(&sm.stage[lrow][lcol]) = va;
      *(float4*)(&sm.stage[lrow][lcol + 4]) = vb;
      __syncthreads();
      if (it + 1 < 4) {
        va = *(const float4*)(xs + ((it + 1) * 16 + lrow) * AN + lcol);
        vb = *(const float4*)(xs + ((it + 1) * 16 + lrow) * AN + lcol + 4);
      }
#pragma unroll
      for (int r = 0; r < 16; ++r) {
        float aa[8], bb[8];
        *(float4*)(aa) = *(const float4*)(&sm.stage[r][i0]);
        *(float4*)(aa + 4) = *(const float4*)(&sm.stage[r][i0 + 4]);
        *(float4*)(bb) = *(const float4*)(&sm.stage[r][j0]);
        *(float4*)(bb + 4) = *(const float4*)(&sm.stage[r][j0 + 4]);
#pragma unroll
        for (int ai = 0; ai < 8; ++ai)
#pragma unroll
          for (int bj = 0; bj < 8; ++bj)
            acc[ai][bj] = fmaf(aa[ai], bb[bj], acc[ai][bj]);
      }
    }
    float* dst = pg + (size_t)b * (AN * AN);
#pragma unroll
    for (int ai = 0; ai < 8; ++ai)
#pragma unroll
      for (int bj = 0; bj < 8; bj += 4)
        *(float4*)(dst + (i0 + ai) * AN + j0 + bj) =
            make_float4(acc[ai][bj], acc[ai][bj + 1], acc[ai][bj + 2],
                        acc[ai][bj + 3]);
    if ((tid >> 4) == (tid & 15)) {
#pragma unroll
      for (int k = 0; k < 8; ++k) pdg[b * AN + i0 + k] = acc[k][k];
    }
    if (tid < AN) {
      float cs = 0.f;
      for (int r = 0; r < 64; ++r) cs += xs[r * AN + tid];
      pc[b * AN + tid] = cs;
    }
    return;
  }

  if (b < R20B0) {
    // ---- per-row std + sign counts, 16 rows/block, float2 cols ----
    int rb = b - RB0;
    double sstd = 0.0, sconc = 0.0;
    for (int rr = 0; rr < 4; ++rr) {
      int t = rb * 16 + w * 4 + rr;
      float2 xv = *(const float2*)(x + (size_t)t * AN + 2 * lane);
      float x0 = xv.x, x1 = xv.y;
      float s = x0 + x1;
#pragma unroll
      for (int o = 32; o; o >>= 1) s += __shfl_xor(s, o);
      float mean = s * (1.0f / AN);
      float d0 = x0 - mean, d1 = x1 - mean;
      float q = d0 * d0 + d1 * d1;
#pragma unroll
      for (int o = 32; o; o >>= 1) q += __shfl_xor(q, o);
      float sd = sqrtf(q / (float)(AN - 1));
      int pk = (int)(x0 < 0.f) + (int)(x1 < 0.f)
             + (((int)(x0 == 0.f) + (int)(x1 == 0.f)) << 10)
             + (((int)(x0 > 0.f) + (int)(x1 > 0.f)) << 20);
#pragma unroll
      for (int o = 32; o; o >>= 1) pk += __shfl_xor(pk, o);
      if (lane == 0) {
        int nn = pk & 1023, nz = (pk >> 10) & 1023, np = (pk >> 20) & 1023;
        sconc += (double)nn * nn + (double)nz * nz + (double)np * np;
        sstd += (double)sd;
        if (t == 0) wsd[WS_STD0] = (double)sd;
        if (t == TN - 1) wsd[WS_STDL] = (double)sd;
      }
    }
    if (lane == 0) { sm.tacc[w][0] = sstd; sm.tacc[w][1] = sconc; }
    __syncthreads();
    if (tid == 0) {
      wsd[WS_BLK + (size_t)b * 2 + 0] =
          sm.tacc[0][0] + sm.tacc[1][0] + sm.tacc[2][0] + sm.tacc[3][0];
      wsd[WS_BLK + (size_t)b * 2 + 1] =
          sm.tacc[0][1] + sm.tacc[1][1] + sm.tacc[2][1] + sm.tacc[3][1];
    }
    return;
  }

  if (b < R10B0) {
    int s0 = (b - R20B0) * 16 + w * 4;
    double cnt = 0.0, dummy = 0.0;
    roll_strip4<20>(x, s0, NW20, lane, cnt, dummy);
    if (lane == 0) { sm.tacc[w][0] = cnt; }
    __syncthreads();
    if (tid == 0)
      wsd[WS_BLK + (size_t)b * 2 + 0] =
          sm.tacc[0][0] + sm.tacc[1][0] + sm.tacc[2][0] + sm.tacc[3][0];
    return;
  }

  {
    int s0 = (b - R10B0) * 16 + w * 4;
    double s10 = 0.0, s10l5 = 0.0;
    roll_strip4<10>(x, s0, NW10, lane, s10, s10l5);
    if (lane == 0) { sm.tacc[w][0] = s10; sm.tacc[w][1] = s10l5; }
    __syncthreads();
    if (tid == 0) {
      wsd[WS_BLK + (size_t)b * 2 + 0] =
          sm.tacc[0][0] + sm.tacc[1][0] + sm.tacc[2][0] + sm.tacc[3][0];
      wsd[WS_BLK + (size_t)b * 2 + 1] =
          sm.tacc[0][1] + sm.tacc[1][1] + sm.tacc[2][1] + sm.tacc[3][1];
    }
  }
}

// ====== phase B: fold partials -> cov -> corr + scalar folds (R6) ========
__global__ void __launch_bounds__(256) k_fold(const float* __restrict__ pc,
                                              const float* __restrict__ pdg,
                                              const float* __restrict__ pg,
                                              double* __restrict__ wsd,
                                              float* __restrict__ corr) {
  __shared__ double r0[256], r1[256], r2[256], r3[256], r4[256];
  int b = blockIdx.x;
  int t = threadIdx.x;
  if (b < 64) {
    __shared__ double muS[AN], dS[AN];
    if (t < AN) {
      double cs = 0.0, dg = 0.0;
      for (int s = 0; s < NB_GRAM; ++s) {
        cs += (double)pc[s * AN + t];
        dg += (double)pdg[s * AN + t];
      }
      double mu = cs / (double)TN;
      muS[t] = mu;
      dS[t] = sqrt(dg - (double)TN * mu * mu);
    }
    __syncthreads();
    int e = b * 256 + t;
    int i = e >> 7, j = e & (AN - 1);
    double cv = 0.0;
    for (int s = 0; s < NB_GRAM; ++s) cv += (double)pg[(size_t)s * (AN * AN) + e];
    cv -= (double)TN * muS[i] * muS[j];
    double c = cv / (dS[i] * dS[j]);
    corr[e] = (float)c;
    r0[t] = c;
    r1[t] = fabs(c);
    r2[t] = (i == j) ? c : 0.0;
    __syncthreads();
    for (int sft = 128; sft; sft >>= 1) {
      if (t < sft) { r0[t] += r0[t + sft]; r1[t] += r1[t + sft]; r2[t] += r2[t + sft]; }
      __syncthreads();
    }
    if (t == 0) {
      wsd[WS_SPEC + b * 3 + 0] = r0[0];
      wsd[WS_SPEC + b * 3 + 1] = r1[0];
      wsd[WS_SPEC + b * 3 + 2] = r2[0];
    }
  } else {
    double a = 0.0, bc = 0.0, cnt = 0.0, s10 = 0.0, s10l5 = 0.0;
    for (int k = RB0 + t; k < NB_WORK; k += 256) {
      const double* p = wsd + WS_BLK + (size_t)k * 2;
      if (k < R20B0) { a += p[0]; bc += p[1]; }
      else if (k < R10B0) cnt += p[0];
      else { s10 += p[0]; s10l5 += p[1]; }
    }
    r0[t] = a; r1[t] = bc; r2[t] = cnt; r3[t] = s10; r4[t] = s10l5;
    __syncthreads();
    for (int sft = 128; sft; sft >>= 1) {
      if (t < sft) {
        r0[t] += r0[t + sft]; r1[t] += r1[t + sft]; r2[t] += r2[t + sft];
        r3[t] += r3[t + sft]; r4[t] += r4[t + sft];
      }
      __syncthreads();
    }
    if (t == 0) {
      wsd[2] = r0[0];   // sumstd
      wsd[3] = r1[0];   // conc
      wsd[4] = r2[0];   // cnt20
      wsd[5] = r3[0];   // sum10
      wsd[6] = r4[0];   // sum10l5
    }
  }
}

// ====== phase C: power iteration + MLP + assembly (single block) =========
__global__ void __launch_bounds__(256) k_spec_tail(
    const float* __restrict__ x, const float* __restrict__ pos,
    const float* __restrict__ w1, const float* __restrict__ b1,
    const float* __restrict__ gamma, const float* __restrict__ beta,
    const float* __restrict__ w2, const float* __restrict__ b2,
    const float* __restrict__ w3, const float* __restrict__ b3,
    const double* __restrict__ wsd, const float* __restrict__ corr,
    float* __restrict__ out) {
  __shared__ float vv[AN], prt[256], un[AN], red[4];
  __shared__ double spec[3];
  __shared__ float f[2 * AN], h1[AN], h2[64], lg[3];
  int t = threadIdx.x;
  int lane = t & 63;
  int w = t >> 6;
  if (t < 64) {                       // wave 0: fold spec partials
    double s0 = wsd[WS_SPEC + t * 3 + 0];
    double s1 = wsd[WS_SPEC + t * 3 + 1];
    double s2 = wsd[WS_SPEC + t * 3 + 2];
#pragma unroll
    for (int o = 32; o; o >>= 1) {
      s0 += __shfl_xor(s0, o);
      s1 += __shfl_xor(s1, o);
      s2 += __shfl_xor(s2, o);
    }
    if (t == 0) { spec[0] = s0; spec[1] = s1; spec[2] = s2; }
  }
  f[t] = (t < AN) ? x[(size_t)(TN - 1) * AN + t] : pos[t - AN];
  if (t < AN) vv[t] = 1.0f;
  __syncthreads();
  // ---- power iteration, 12 iters, corr L2-hot ----
  int ri = t & (AN - 1), hh = t >> 7;
  const float4* rp = (const float4*)(corr + ri * AN + hh * 64);
  float lam = 0.0f;
  for (int it = 0; it < 12; ++it) {
    const float4* vp = (const float4*)(&vv[hh * 64]);
    float acc = 0.f;
#pragma unroll
    for (int k = 0; k < 16; ++k) {
      float4 a = rp[k], bv = vp[k];
      acc += a.x * bv.x + a.y * bv.y + a.z * bv.z + a.w * bv.w;
    }
    prt[t] = acc;
    __syncthreads();
    if (t < AN) {
      float u = prt[t] + prt[t + 128];
      un[t] = u;
      float sq = u * u;
#pragma unroll
      for (int o = 32; o; o >>= 1) sq += __shfl_xor(sq, o);
      if (lane == 0) red[w] = sq;
    }
    __syncthreads();
    lam = sqrtf(red[0] + red[1]);
    if (t < AN) vv[t] = un[t] / lam;
    __syncthreads();
  }
  // ---- MLP: layer 1 split over 2 half-K groups ----
  {
    int n = t & 127, h = t >> 7;
    float acc = 0.f;
    const float* wcol = w1 + h * 128 * AN + n;
    const float* fv = f + h * 128;
    for (int k = 0; k < 128; ++k) acc = fmaf(fv[k], wcol[k * AN], acc);
    prt[t] = acc;
  }
  __syncthreads();
  if (t < AN) {
    float acc = b1[t] + prt[t] + prt[t + 128];
    acc = fmaxf(acc, 0.0f);
    h1[t] = gamma[t] * (acc / sqrtf(1.0f + 1e-5f)) + beta[t];
  }
  __syncthreads();
  if (t < 64) {
    float acc = b2[t];
    for (int k = 0; k < AN; ++k) acc = fmaf(h1[k], w2[k * 64 + t], acc);
    h2[t] = fmaxf(acc, 0.0f);
  }
  __syncthreads();
  if (t < 3) {
    float acc = b3[t];
    for (int k = 0; k < 64; ++k) acc = fmaf(h2[k], w3[k * 3 + t], acc);
    lg[t] = acc;
  }
  __syncthreads();
  if (t != 0) return;
  float m = fmaxf(lg[0], fmaxf(lg[1], lg[2]));
  float e0 = expf(lg[0] - m), e1 = expf(lg[1] - m), e2 = expf(lg[2] - m);
  double sev = (double)(e2 / (e0 + e1 + e2));
  double sumstd = wsd[2], conc = wsd[3], cnt20 = wsd[4];
  double sum10 = wsd[5], sum10l5 = wsd[6];
  double avg_disp = sumstd / (double)TN;
  double trend = -(wsd[WS_STDL] - wsd[WS_STD0]) / (double)(TN - 1);
  double hi = trend / (avg_disp + 1e-6) + 0.5;
  hi = fmin(1.0, fmax(0.0, hi));
  double avg_corr = (spec[0] - spec[2]) / ((double)AN * (AN - 1));
  double sync_ind = (double)lam / (double)AN;
  double sync_risk = fmin(1.0, sync_ind * avg_corr);
  double pl = cnt20 / (double)(TN - 20);
  double rd = 1.0 - spec[1] / ((double)AN * AN);
  double pasum = 0.0, pamax = 0.0;
  for (int k = 0; k < AN; ++k) {
    double pa = fabs((double)pos[k]);
    pasum += pa;
    if (pa > pamax) pamax = pa;
  }
  double pd = 1.0 - pamax / pasum;
  double dl = 1.0 - sqrt(rd * pd);
  double recent = sum10l5 / 5.0;
  double hist = (sum10 - sum10l5) / (double)(TN - 10 - 5);
  double sraw = (recent - hist) / hist;
  sraw = fmin(1.0, fmax(0.0, sraw));
  double surge = (hist > 0.0) ? sraw : 0.0;
  double ac = (conc / (double)TN - (double)AN) / ((double)AN * (AN - 1));
  double pcup = fmin(1.0, fmax(0.0, (ac - 0.5) * 2.0));
  double cr = (hi + sync_risk + dl) / 3.0;
  out[0] = (float)hi;
  out[1] = (float)sev;
  out[2] = (float)sync_risk;
  out[3] = (float)pl;
  out[4] = (float)dl;
  out[5] = (float)surge;
  out[6] = (float)pcup;
  out[7] = (float)cr;
}

extern "C" void kernel_launch(void* const* d_in, const int* in_sizes, int n_in,
                              void* d_out, int out_size, void* d_ws, size_t ws_size,
                              hipStream_t stream) {
  const float* x     = (const float*)d_in[0];
  const float* pos   = (const float*)d_in[1];
  const float* w1    = (const float*)d_in[2];
  const float* b1    = (const float*)d_in[3];
  const float* gamma = (const float*)d_in[4];
  const float* beta  = (const float*)d_in[5];
  const float* w2    = (const float*)d_in[6];
  const float* b2    = (const float*)d_in[7];
  const float* w3    = (const float*)d_in[8];
  const float* b3    = (const float*)d_in[9];
  float* out = (float*)d_out;
  double* wsd = (double*)d_ws;
  float* corr = (float*)(wsd + WS_DEND);               // [16384]
  float* pc   = corr + AN * AN;                        // [128*128]
  float* pdg  = pc + NB_GRAM * AN;                     // [128*128]
  float* pg   = pdg + NB_GRAM * AN;                    // [128*16384]

  k_main<<<NB_WORK, 256, 0, stream>>>(x, wsd, pc, pdg, pg);
  k_fold<<<65, 256, 0, stream>>>(pc, pdg, pg, wsd, corr);
  k_spec_tail<<<1, 256, 0, stream>>>(x, pos, w1, b1, gamma, beta, w2, b2,
                                     w3, b3, wsd, corr, out);
}